// Round 1
// 159.966 us; speedup vs baseline: 1.0678x; 1.0678x over previous
//
#include <hip/hip_runtime.h>
#include <hip/hip_bf16.h>
#include <cstddef>
#include <math.h>

// Problem constants (from reference)
#define N_NODES 16384   // B*A
#define DIN 64
#define HID 128
#define SCALE_F 0.17677669529663687f  // 1/sqrt(32)

using bf16x8 = __attribute__((ext_vector_type(8))) short;   // 8 bf16 = 4 VGPRs
using f32x4  = __attribute__((ext_vector_type(4))) float;   // MFMA acc

__device__ __forceinline__ ushort f2b(float x) {
  __hip_bfloat16 h = __float2bfloat16(x);
  return *(ushort*)&h;
}
__device__ __forceinline__ float b2f(ushort u) {
  __hip_bfloat16 h = *(__hip_bfloat16*)&u;
  return __bfloat162float(h);
}
// fp32 -> 2-way split (hi+lo), err ~2^-17 |x|
__device__ __forceinline__ void split1(float x, ushort& h, ushort& l) {
  h = f2b(x);
  l = f2b(x - b2f(h));
}
// fp32 -> 3-way split (a+b+c), err ~2^-27 |x|  (F/M path, proven)
__device__ __forceinline__ void split3(float x, ushort& a, ushort& b, ushort& c) {
  a = f2b(x);
  float r1 = x - b2f(a);
  b = f2b(r1);
  c = f2b(r1 - b2f(b));
}

#define MFMA(d, A, B) d = __builtin_amdgcn_mfma_f32_16x16x32_bf16(A, B, d, 0, 0, 0)

// ---------------- merged prep: G, M0, M1, W1/W2 splits, zero(out) ----------------
// block ranges: [0] G | [1,129) M0 | [129,385) M1 | [385,769) splitW | [769,833) zero

__global__ __launch_bounds__(256) void prep_all_kernel(
    const float* __restrict__ Wq0, const float* __restrict__ Wk0,
    const float* __restrict__ Wq1, const float* __restrict__ Wk1,
    float* __restrict__ G,
    const float* __restrict__ Wv0, const float* __restrict__ Wo0,
    ushort* __restrict__ M0a, ushort* __restrict__ M0b, ushort* __restrict__ M0c,
    const float* __restrict__ Wv1, const float* __restrict__ Wo1,
    ushort* __restrict__ M1a, ushort* __restrict__ M1b, ushort* __restrict__ M1c,
    const float* __restrict__ W1, ushort* __restrict__ W1hi, ushort* __restrict__ W1lo,
    const float* __restrict__ W2, ushort* __restrict__ W2hi, ushort* __restrict__ W2lo,
    unsigned long long* __restrict__ out64)
{
  int blk = blockIdx.x, t = threadIdx.x;
  if (blk == 0) {
    if (t >= 32) return;
    int l = t >> 4, h = (t >> 2) & 3, a = (t >> 1) & 1, b = t & 1;
    const float* Wq = l ? Wq1 : Wq0;
    const float* Wk = l ? Wk1 : Wk0;
    float acc = 0.f;
    for (int c = 0; c < 128; c++)
      acc += Wq[(h * 128 + c) * 2 + a] * Wk[(h * 128 + c) * 2 + b];
    G[t] = acc;
  } else if (blk < 385) {
    // folded M = Wv^T-contract-Wo, triple-split
    int D, idx;
    const float *Wv, *Wo;
    ushort *Ma, *Mb, *Mc;
    if (blk < 129) { D = DIN; idx = (blk - 1) * 256 + t; Wv = Wv0; Wo = Wo0; Ma = M0a; Mb = M0b; Mc = M0c; }
    else           { D = HID; idx = (blk - 129) * 256 + t; Wv = Wv1; Wo = Wo1; Ma = M1a; Mb = M1b; Mc = M1c; }
    int K4 = 4 * D;
    int o = idx / K4, hd = idx - o * K4;
    int h = hd / D, d = hd - h * D;
    const float* wv = Wv + (size_t)(h * 128) * D + d;
    const float* wo = Wo + (size_t)o * 512 + h * 128;
    float acc = 0.f;
    for (int c = 0; c < 128; c++)
      acc += wv[(size_t)c * D] * wo[c];
    split3(acc, Ma[idx], Mb[idx], Mc[idx]);
  } else if (blk < 769) {
    int i = (blk - 385) * 256 + t;
    if (i < 256 * 128) split1(W1[i], W1hi[i], W1lo[i]);
    int j = i - 256 * 128;
    if (j >= 0 && j < 256 * 256) split1(W2[j], W2hi[j], W2lo[j]);
  } else {
    int i = (blk - 769) * 256 + t;
    if (i < N_NODES) out64[i] = 0ull;   // zero output (atomic W3 accumulation)
  }
}

// ---------------- fully fused: mask build + 2-layer GAT + 3-layer MLP ----------------
// 512 threads / block, one block per 64-node graph block (grid = 256 = 1/CU).
// R13 change: the softmax/A-build was 8x redundant (every wave recomputed all
// 4 heads x 4 dst tiles; counters: VALUBusy 48%, MfmaUtil 18% -> VALU-bound).
// Now the 16 (h,mtd) pairs are distributed 2-per-wave, computed ONCE, and the
// split2 A-fragments (lane-layout identical for all waves -- they depend only
// on lane, not wave) are staged through a 64KB LDS region (lane-linear b128,
// conflict-free). A-math is bit-identical to R11 (same __expf/split1/order).
// LDS grows 64KB -> 116KB: free, grid=256 already pins 1 block/CU.
// MLP pA/pB planes moved into the (dead-by-then) A region -> old B7 dropped.
// NOTE (R12 post-mortem): head-pairing for 2x MFMA ILP regressed 81->84us
// (bottleneck is not MFMA chain ILP).

#define PF 136   // F plane pitch (ushort)

// LDS layout (ushort indices):
//   sFa [0,8704) | sFb [8704,17408) | sFc [17408,26112)
//   pxs [26112,26240) | pys [26240,26368) | smask [26368,26624)
//   A-frags [26624,59392)  (16 pairs x 4 slots x 512 ushorts = 64KB)
//   MLP: pA [26624,43008) | pB [43008,59392)  (reuses dead A region)
#define AFRAG_OFF 26624
#define LDS_USHORTS 59392

template <int KD>
__device__ __forceinline__ void gat_layer(
    int wave, int lane, int lm, int lq,
    const ushort* sFa, const ushort* sFb, const ushort* sFc,
    ushort* aA,
    const float* psx, const float* psy,
    const float* pdx, const float* pdy,
    const unsigned long long* m64,
    const float* __restrict__ G,
    const ushort* __restrict__ Ma, const ushort* __restrict__ Mb,
    const ushort* __restrict__ Mc,
    f32x4 hacc[4])
{
  // ---- A-build, deduplicated: wave w owns mtd = w&3, heads {w>>2, (w>>2)+2}.
  // Selects below are static-index (rule #20: no runtime-indexed reg arrays).
  {
    int wm = wave & 3;
    float pdxm = (wm & 2) ? ((wm & 1) ? pdx[3] : pdx[2]) : ((wm & 1) ? pdx[1] : pdx[0]);
    float pdym = (wm & 2) ? ((wm & 1) ? pdy[3] : pdy[2]) : ((wm & 1) ? pdy[1] : pdy[0]);
    unsigned long long mm = (wm & 2) ? ((wm & 1) ? m64[3] : m64[2])
                                     : ((wm & 1) ? m64[1] : m64[0]);
    unsigned mb0 = (unsigned)((mm >> (8 * lq)) & 0xFF);
    unsigned mb1 = (unsigned)((mm >> (32 + 8 * lq)) & 0xFF);
#pragma unroll
    for (int pi = 0; pi < 2; pi++) {
      int h = (wave >> 2) + 2 * pi;
      float g0 = G[h * 4], g1 = G[h * 4 + 1], g2 = G[h * 4 + 2], g3 = G[h * 4 + 3];
      float a0 = (g0 * pdxm + g2 * pdym) * SCALE_F;
      float a1 = (g1 * pdxm + g3 * pdym) * SCALE_F;
      float sshift = a0 * pdxm + a1 * pdym;
      float e[16];
      float sum = 0.f;
#pragma unroll
      for (int j = 0; j < 8; j++) {
        e[j]     = ((mb0 >> j) & 1) ? __expf(a0 * psx[j] + a1 * psy[j] - sshift) : 0.f;
        e[8 + j] = ((mb1 >> j) & 1) ? __expf(a0 * psx[8 + j] + a1 * psy[8 + j] - sshift) : 0.f;
        sum += e[j] + e[8 + j];
      }
      sum += __shfl_xor(sum, 16);
      sum += __shfl_xor(sum, 32);
      float inv = 1.f / sum;
      bf16x8 Aa0, Aa1, Ab0, Ab1;
#pragma unroll
      for (int j = 0; j < 8; j++) {
        ushort ua, ub;
        split1(e[j] * inv, ua, ub);     Aa0[j] = (short)ua; Ab0[j] = (short)ub;
        split1(e[8 + j] * inv, ua, ub); Aa1[j] = (short)ua; Ab1[j] = (short)ub;
      }
      int sbase = (h * 4 + wm) * 2048 + lane * 8;
      *(bf16x8*)&aA[sbase]        = Aa0;
      *(bf16x8*)&aA[sbase + 512]  = Aa1;
      *(bf16x8*)&aA[sbase + 1024] = Ab0;
      *(bf16x8*)&aA[sbase + 1536] = Ab1;
    }
  }
  __syncthreads();   // BA: all 16 pairs' A-frags visible

  const int K4 = 4 * KD;
  const int o = 16 * wave + lm;
#pragma unroll
  for (int i = 0; i < 4; i++) hacc[i] = (f32x4){0.f, 0.f, 0.f, 0.f};

#pragma unroll 1
  for (int h = 0; h < 4; h++) {
    f32x4 y[4];
#pragma unroll
    for (int i = 0; i < 4; i++) y[i] = (f32x4){0.f, 0.f, 0.f, 0.f};
#pragma unroll 1
    for (int kf = 0; kf < KD / 32; kf++) {
      size_t boff = (size_t)o * K4 + h * KD + kf * 32 + lq * 8;
      bf16x8 ma = *(const bf16x8*)&Ma[boff];
      bf16x8 mb = *(const bf16x8*)&Mb[boff];
      bf16x8 mc = *(const bf16x8*)&Mc[boff];
#pragma unroll
      for (int mp = 0; mp < 2; mp++) {
        int f0 = (mp * 32 + lm) * PF + kf * 32 + lq * 8;
        int f1 = (mp * 32 + 16 + lm) * PF + kf * 32 + lq * 8;
        bf16x8 fa0 = *(const bf16x8*)&sFa[f0], fa1 = *(const bf16x8*)&sFa[f1];
        bf16x8 fb0 = *(const bf16x8*)&sFb[f0], fb1 = *(const bf16x8*)&sFb[f1];
        bf16x8 fc0 = *(const bf16x8*)&sFc[f0], fc1 = *(const bf16x8*)&sFc[f1];
        f32x4 y0 = y[mp * 2], y1 = y[mp * 2 + 1];
        MFMA(y0, fa0, ma); MFMA(y1, fa1, ma);
        MFMA(y0, fa0, mb); MFMA(y1, fa1, mb);
        MFMA(y0, fb0, ma); MFMA(y1, fb1, ma);
        MFMA(y0, fa0, mc); MFMA(y1, fa1, mc);
        MFMA(y0, fc0, ma); MFMA(y1, fc1, ma);
        MFMA(y0, fb0, mb); MFMA(y1, fb1, mb);
        y[mp * 2] = y0; y[mp * 2 + 1] = y1;
      }
    }
    // redistribute y (C-layout) -> B-frags via shuffles, split2
    bf16x8 Ya[2], Yb[2];
#pragma unroll
    for (int kb = 0; kb < 2; kb++) {
#pragma unroll
      for (int j = 0; j < 8; j++) {
        int sl = ((2 * lq + (j >> 2)) & 3) * 16 + lm;
        float v0 = __shfl(y[2 * kb][j & 3], sl);
        float v1 = __shfl(y[2 * kb + 1][j & 3], sl);
        float v = (lq & 2) ? v1 : v0;
        ushort ua, ub;
        split1(v, ua, ub);
        Ya[kb][j] = (short)ua; Yb[kb][j] = (short)ub;
      }
    }
    // A@Y per dst tile, A-frags from LDS (lane-linear b128, conflict-free)
#pragma unroll
    for (int mtd = 0; mtd < 4; mtd++) {
      int abase = (h * 4 + mtd) * 2048 + lane * 8;
      bf16x8 Aa0 = *(const bf16x8*)&aA[abase];
      bf16x8 Aa1 = *(const bf16x8*)&aA[abase + 512];
      bf16x8 Ab0 = *(const bf16x8*)&aA[abase + 1024];
      bf16x8 Ab1 = *(const bf16x8*)&aA[abase + 1536];
      MFMA(hacc[mtd], Aa0, Ya[0]);
      MFMA(hacc[mtd], Aa0, Yb[0]);
      MFMA(hacc[mtd], Ab0, Ya[0]);
      MFMA(hacc[mtd], Ab0, Yb[0]);
      MFMA(hacc[mtd], Aa1, Ya[1]);
      MFMA(hacc[mtd], Aa1, Yb[1]);
      MFMA(hacc[mtd], Ab1, Ya[1]);
      MFMA(hacc[mtd], Ab1, Yb[1]);
    }
  }
}

__global__ __attribute__((amdgpu_flat_work_group_size(512, 512), amdgpu_waves_per_eu(2)))
void fused_gat_kernel(
    const float* __restrict__ x, const float* __restrict__ pos,
    const int* __restrict__ srcp, const int* __restrict__ dstp,
    const float* __restrict__ G,
    const ushort* __restrict__ M0a, const ushort* __restrict__ M0b, const ushort* __restrict__ M0c,
    const ushort* __restrict__ M1a, const ushort* __restrict__ M1b, const ushort* __restrict__ M1c,
    const float* __restrict__ bo0, const float* __restrict__ bo1,
    const ushort* __restrict__ W1hi, const ushort* __restrict__ W1lo, const float* __restrict__ b1,
    const ushort* __restrict__ W2hi, const ushort* __restrict__ W2lo, const float* __restrict__ b2,
    const float* __restrict__ W3, const float* __restrict__ b3,
    float* __restrict__ outp)
{
  __shared__ __align__(16) ushort uBig[LDS_USHORTS];
  ushort* sFa = uBig;
  ushort* sFb = uBig + 8704;
  ushort* sFc = uBig + 17408;
  float* pxs = (float*)(uBig + 26112);
  float* pys = (float*)(uBig + 26240);
  unsigned long long* smask = (unsigned long long*)(uBig + 26368);
  ushort* aA = uBig + AFRAG_OFF;
  ushort* pA = uBig + AFRAG_OFF;            // MLP reuse of A region (dead by B6)
  ushort* pB = uBig + AFRAG_OFF + 16384;

  int b = blockIdx.x, t = threadIdx.x;
  int wave = t >> 6, lane = t & 63, lm = lane & 15, lq = lane >> 4;

  if (t < 64) {
    pxs[t] = pos[(b * 64 + t) * 2];
    pys[t] = pos[(b * 64 + t) * 2 + 1];
    smask[t] = 1ull << t;   // self-loop bit
  }
  // stage X (64x64 fp32) -> triple-split planes
  {
    const float4* gx = (const float4*)(x + (size_t)b * 64 * DIN);
#pragma unroll
    for (int i = 0; i < 2; i++) {
      int idx = t + i * 512;
      float4 v = gx[idx];
      int r = idx >> 4, c = (idx & 15) * 4;
      ushort4 ua, ub, uc;
      split3(v.x, ua.x, ub.x, uc.x); split3(v.y, ua.y, ub.y, uc.y);
      split3(v.z, ua.z, ub.z, uc.z); split3(v.w, ua.w, ub.w, uc.w);
      *(ushort4*)&sFa[r * PF + c] = ua;
      *(ushort4*)&sFb[r * PF + c] = ub;
      *(ushort4*)&sFc[r * PF + c] = uc;
    }
  }
  __syncthreads();   // B1: smask init + X visible
  // adjacency from this block's own 448 kNN edge rows (reference (B,A,K) C-order)
  if (t < 448) {
    int s = srcp[b * 448 + t];
    int d = dstp[b * 448 + t];
    atomicOr(&smask[d & 63], 1ull << (s & 63));
  }
  __syncthreads();   // B2
  unsigned long long m64[4];
#pragma unroll
  for (int mtd = 0; mtd < 4; mtd++) m64[mtd] = smask[mtd * 16 + lm];

  float psx[16], psy[16], pdx[4], pdy[4];
#pragma unroll
  for (int j = 0; j < 8; j++) {
    psx[j] = pxs[8 * lq + j];          psy[j] = pys[8 * lq + j];
    psx[8 + j] = pxs[32 + 8 * lq + j]; psy[8 + j] = pys[32 + 8 * lq + j];
  }
#pragma unroll
  for (int mtd = 0; mtd < 4; mtd++) {
    pdx[mtd] = pxs[mtd * 16 + lm];
    pdy[mtd] = pys[mtd * 16 + lm];
  }

  f32x4 hacc[4];
  gat_layer<DIN>(wave, lane, lm, lq, sFa, sFb, sFc, aA, psx, psy, pdx, pdy, m64,
                 G, M0a, M0b, M0c, hacc);
  __syncthreads();   // B3: layer-0 F + A reads done
  int o = 16 * wave + lm;
  {
    float bv = bo0[o];
#pragma unroll
    for (int mtd = 0; mtd < 4; mtd++)
#pragma unroll
      for (int r = 0; r < 4; r++) {
        int dst = mtd * 16 + lq * 4 + r;
        ushort ua, ub, uc;
        split3(tanhf(hacc[mtd][r] + bv), ua, ub, uc);
        sFa[dst * PF + o] = ua;
        sFb[dst * PF + o] = ub;
        sFc[dst * PF + o] = uc;
      }
  }
  __syncthreads();   // B4
  gat_layer<HID>(wave, lane, lm, lq, sFa, sFb, sFc, aA, psx, psy, pdx, pdy, m64,
                 G + 16, M1a, M1b, M1c, hacc);
  // h2 in regs
  float h2v[4][4];
  {
    float bv = bo1[o];
#pragma unroll
    for (int mtd = 0; mtd < 4; mtd++)
#pragma unroll
      for (int r = 0; r < 4; r++)
        h2v[mtd][r] = tanhf(hacc[mtd][r] + bv);
  }
  __syncthreads();   // B5: layer-1 sF + A reads done
  // store h2 split2 into sFa/sFb
#pragma unroll
  for (int mtd = 0; mtd < 4; mtd++)
#pragma unroll
    for (int r = 0; r < 4; r++) {
      int dst = mtd * 16 + lq * 4 + r;
      ushort hh, ll;
      split1(h2v[mtd][r], hh, ll);
      sFa[dst * PF + o] = hh;
      sFb[dst * PF + o] = ll;
    }
  __syncthreads();   // B6
  // ---- W1: out1 = relu(h2 @ W1^T + b1); wave cols [32w, 32w+32) ----
  f32x4 y1[2][4];
#pragma unroll
  for (int ti = 0; ti < 2; ti++)
#pragma unroll
    for (int mtd = 0; mtd < 4; mtd++) y1[ti][mtd] = (f32x4){0.f, 0.f, 0.f, 0.f};
#pragma unroll 1
  for (int kf = 0; kf < 4; kf++) {
    int ko = kf * 32 + lq * 8;
    bf16x8 bh0 = *(const bf16x8*)&W1hi[(size_t)(32 * wave + lm) * 128 + ko];
    bf16x8 bl0 = *(const bf16x8*)&W1lo[(size_t)(32 * wave + lm) * 128 + ko];
    bf16x8 bh1 = *(const bf16x8*)&W1hi[(size_t)(32 * wave + 16 + lm) * 128 + ko];
    bf16x8 bl1 = *(const bf16x8*)&W1lo[(size_t)(32 * wave + 16 + lm) * 128 + ko];
#pragma unroll
    for (int mtd = 0; mtd < 4; mtd++) {
      bf16x8 ah = *(const bf16x8*)&sFa[(mtd * 16 + lm) * PF + ko];
      bf16x8 al = *(const bf16x8*)&sFb[(mtd * 16 + lm) * PF + ko];
      MFMA(y1[0][mtd], ah, bh0);
      MFMA(y1[0][mtd], ah, bl0);
      MFMA(y1[0][mtd], al, bh0);
      MFMA(y1[1][mtd], ah, bh1);
      MFMA(y1[1][mtd], ah, bl1);
      MFMA(y1[1][mtd], al, bh1);
    }
  }
  // (old B7 removed: pA/pB now live in the dead A-frag region, disjoint from
  //  the sFa/sFb h2 planes read above; B8 below still orders store->read)
  // store out1 split2, XOR-swizzled: elem (row,k) at row*256 + (k ^ ((row&15)<<3))
#pragma unroll
  for (int ti = 0; ti < 2; ti++) {
    int col = 32 * wave + ti * 16 + lm;
    float bv = b1[col];
#pragma unroll
    for (int mtd = 0; mtd < 4; mtd++)
#pragma unroll
      for (int r = 0; r < 4; r++) {
        int row = mtd * 16 + lq * 4 + r;
        float v = fmaxf(y1[ti][mtd][r] + bv, 0.f);
        ushort hh, ll;
        split1(v, hh, ll);
        int cc = col ^ ((row & 15) << 3);
        pA[row * 256 + cc] = hh;
        pB[row * 256 + cc] = ll;
      }
  }
  __syncthreads();   // B8
  // ---- W2 + fused W3 ----
  f32x4 y2[2][4];
#pragma unroll
  for (int ti = 0; ti < 2; ti++)
#pragma unroll
    for (int mtd = 0; mtd < 4; mtd++) y2[ti][mtd] = (f32x4){0.f, 0.f, 0.f, 0.f};
#pragma unroll 1
  for (int kf = 0; kf < 8; kf++) {
    int ko = kf * 32 + lq * 8;
    bf16x8 bh0 = *(const bf16x8*)&W2hi[(size_t)(32 * wave + lm) * 256 + ko];
    bf16x8 bl0 = *(const bf16x8*)&W2lo[(size_t)(32 * wave + lm) * 256 + ko];
    bf16x8 bh1 = *(const bf16x8*)&W2hi[(size_t)(32 * wave + 16 + lm) * 256 + ko];
    bf16x8 bl1 = *(const bf16x8*)&W2lo[(size_t)(32 * wave + 16 + lm) * 256 + ko];
#pragma unroll
    for (int mtd = 0; mtd < 4; mtd++) {
      int row = mtd * 16 + lm;
      int cc = ko ^ ((row & 15) << 3);
      bf16x8 ah = *(const bf16x8*)&pA[row * 256 + cc];
      bf16x8 al = *(const bf16x8*)&pB[row * 256 + cc];
      MFMA(y2[0][mtd], ah, bh0);
      MFMA(y2[0][mtd], ah, bl0);
      MFMA(y2[0][mtd], al, bh0);
      MFMA(y2[1][mtd], ah, bh1);
      MFMA(y2[1][mtd], ah, bl1);
      MFMA(y2[1][mtd], al, bh1);
    }
  }
  // W3 epilogue: per-row dot over this wave's 32 cols, lm-reduce, atomicAdd
  {
    int c0 = 32 * wave + lm, c1 = c0 + 16;
    float w300 = W3[c0], w301 = W3[c1];
    float w310 = W3[256 + c0], w311 = W3[256 + c1];
    float b20 = b2[c0], b21 = b2[c1];
    float bb0 = (wave == 0) ? b3[0] : 0.f;
    float bb1 = (wave == 0) ? b3[1] : 0.f;
#pragma unroll
    for (int mtd = 0; mtd < 4; mtd++)
#pragma unroll
      for (int r = 0; r < 4; r++) {
        float va = fmaxf(y2[0][mtd][r] + b20, 0.f);
        float vb = fmaxf(y2[1][mtd][r] + b21, 0.f);
        float s0 = va * w300 + vb * w301;
        float s1 = va * w310 + vb * w311;
        s0 += __shfl_xor(s0, 1); s0 += __shfl_xor(s0, 2);
        s0 += __shfl_xor(s0, 4); s0 += __shfl_xor(s0, 8);
        s1 += __shfl_xor(s1, 1); s1 += __shfl_xor(s1, 2);
        s1 += __shfl_xor(s1, 4); s1 += __shfl_xor(s1, 8);
        if (lm == 0) {
          int row = b * 64 + mtd * 16 + lq * 4 + r;
          atomicAdd(&outp[row * 2 + 0], s0 + bb0);
          atomicAdd(&outp[row * 2 + 1], s1 + bb1);
        }
      }
  }
}

// ---------------- launch ----------------

extern "C" void kernel_launch(void* const* d_in, const int* in_sizes, int n_in,
                              void* d_out, int out_size, void* d_ws, size_t ws_size,
                              hipStream_t stream) {
  const float* x     = (const float*)d_in[0];
  const float* pos   = (const float*)d_in[1];
  const int*   ei    = (const int*)d_in[2];
  const float* l0_Wq = (const float*)d_in[3];
  const float* l0_Wk = (const float*)d_in[4];
  const float* l0_Wv = (const float*)d_in[5];
  const float* l0_Wo = (const float*)d_in[6];
  const float* l0_bo = (const float*)d_in[7];
  const float* l1_Wq = (const float*)d_in[8];
  const float* l1_Wk = (const float*)d_in[9];
  const float* l1_Wv = (const float*)d_in[10];
  const float* l1_Wo = (const float*)d_in[11];
  const float* l1_bo = (const float*)d_in[12];
  const float* W1    = (const float*)d_in[13];
  const float* b1    = (const float*)d_in[14];
  const float* W2    = (const float*)d_in[15];
  const float* b2    = (const float*)d_in[16];
  const float* W3    = (const float*)d_in[17];
  const float* b3    = (const float*)d_in[18];
  float* outp = (float*)d_out;

  int E = in_sizes[2] / 2;
  const int* srcp = ei;
  const int* dstp = ei + E;

  char* base = (char*)d_ws;
  size_t off = 0;
  auto alloc = [&](size_t bytes) -> void* {
    void* p = base + off;
    off = (off + bytes + 255) & ~(size_t)255;
    return p;
  };
  float*  G   = (float*)alloc(32 * sizeof(float));
  ushort* M0a = (ushort*)alloc((size_t)128 * 256 * 2);
  ushort* M0b = (ushort*)alloc((size_t)128 * 256 * 2);
  ushort* M0c = (ushort*)alloc((size_t)128 * 256 * 2);
  ushort* M1a = (ushort*)alloc((size_t)128 * 512 * 2);
  ushort* M1b = (ushort*)alloc((size_t)128 * 512 * 2);
  ushort* M1c = (ushort*)alloc((size_t)128 * 512 * 2);
  ushort* W1hi = (ushort*)alloc((size_t)256 * 128 * 2);
  ushort* W1lo = (ushort*)alloc((size_t)256 * 128 * 2);
  ushort* W2hi = (ushort*)alloc((size_t)256 * 256 * 2);
  ushort* W2lo = (ushort*)alloc((size_t)256 * 256 * 2);

  // prep: G, M folds, W splits, zero(out)
  prep_all_kernel<<<833, 256, 0, stream>>>(
      l0_Wq, l0_Wk, l1_Wq, l1_Wk, G,
      l0_Wv, l0_Wo, M0a, M0b, M0c,
      l1_Wv, l1_Wo, M1a, M1b, M1c,
      W1, W1hi, W1lo, W2, W2hi, W2lo,
      (unsigned long long*)outp);

  // fully fused network
  fused_gat_kernel<<<N_NODES / 64, 512, 0, stream>>>(
      x, pos, srcp, dstp, G, M0a, M0b, M0c, M1a, M1b, M1c, l0_bo, l1_bo,
      W1hi, W1lo, b1, W2hi, W2lo, b2, W3, b3, outp);

  (void)n_in; (void)out_size; (void)ws_size;
}

// Round 2
// 151.655 us; speedup vs baseline: 1.1263x; 1.0548x over previous
//
#include <hip/hip_runtime.h>
#include <hip/hip_bf16.h>
#include <cstddef>
#include <math.h>

// Problem constants (from reference)
#define N_NODES 16384   // B*A
#define DIN 64
#define HID 128
#define SCALE_F 0.17677669529663687f  // 1/sqrt(32)

using bf16x8 = __attribute__((ext_vector_type(8))) short;   // 8 bf16 = 4 VGPRs
using f32x4  = __attribute__((ext_vector_type(4))) float;   // MFMA acc

__device__ __forceinline__ ushort f2b(float x) {
  __hip_bfloat16 h = __float2bfloat16(x);
  return *(ushort*)&h;
}
__device__ __forceinline__ float b2f(ushort u) {
  __hip_bfloat16 h = *(__hip_bfloat16*)&u;
  return __bfloat162float(h);
}
// fp32 -> 2-way split (hi+lo), err ~2^-17 |x|
__device__ __forceinline__ void split1(float x, ushort& h, ushort& l) {
  h = f2b(x);
  l = f2b(x - b2f(h));
}
// fp32 -> 3-way split (a+b+c), err ~2^-27 |x|  (F/M path, proven)
__device__ __forceinline__ void split3(float x, ushort& a, ushort& b, ushort& c) {
  a = f2b(x);
  float r1 = x - b2f(a);
  b = f2b(r1);
  c = f2b(r1 - b2f(b));
}

#define MFMA(d, A, B) d = __builtin_amdgcn_mfma_f32_16x16x32_bf16(A, B, d, 0, 0, 0)

// ---------------- merged prep: G, M0, M1, W1/W2 splits, zero(out) ----------------
// block ranges: [0] G | [1,129) M0 | [129,385) M1 | [385,769) splitW | [769,833) zero

__global__ __launch_bounds__(256) void prep_all_kernel(
    const float* __restrict__ Wq0, const float* __restrict__ Wk0,
    const float* __restrict__ Wq1, const float* __restrict__ Wk1,
    float* __restrict__ G,
    const float* __restrict__ Wv0, const float* __restrict__ Wo0,
    ushort* __restrict__ M0a, ushort* __restrict__ M0b, ushort* __restrict__ M0c,
    const float* __restrict__ Wv1, const float* __restrict__ Wo1,
    ushort* __restrict__ M1a, ushort* __restrict__ M1b, ushort* __restrict__ M1c,
    const float* __restrict__ W1, ushort* __restrict__ W1hi, ushort* __restrict__ W1lo,
    const float* __restrict__ W2, ushort* __restrict__ W2hi, ushort* __restrict__ W2lo,
    unsigned long long* __restrict__ out64)
{
  int blk = blockIdx.x, t = threadIdx.x;
  if (blk == 0) {
    if (t >= 32) return;
    int l = t >> 4, h = (t >> 2) & 3, a = (t >> 1) & 1, b = t & 1;
    const float* Wq = l ? Wq1 : Wq0;
    const float* Wk = l ? Wk1 : Wk0;
    float acc = 0.f;
    for (int c = 0; c < 128; c++)
      acc += Wq[(h * 128 + c) * 2 + a] * Wk[(h * 128 + c) * 2 + b];
    G[t] = acc;
  } else if (blk < 385) {
    // folded M = Wv^T-contract-Wo, triple-split
    int D, idx;
    const float *Wv, *Wo;
    ushort *Ma, *Mb, *Mc;
    if (blk < 129) { D = DIN; idx = (blk - 1) * 256 + t; Wv = Wv0; Wo = Wo0; Ma = M0a; Mb = M0b; Mc = M0c; }
    else           { D = HID; idx = (blk - 129) * 256 + t; Wv = Wv1; Wo = Wo1; Ma = M1a; Mb = M1b; Mc = M1c; }
    int K4 = 4 * D;
    int o = idx / K4, hd = idx - o * K4;
    int h = hd / D, d = hd - h * D;
    const float* wv = Wv + (size_t)(h * 128) * D + d;
    const float* wo = Wo + (size_t)o * 512 + h * 128;
    float acc = 0.f;
    for (int c = 0; c < 128; c++)
      acc += wv[(size_t)c * D] * wo[c];
    split3(acc, Ma[idx], Mb[idx], Mc[idx]);
  } else if (blk < 769) {
    int i = (blk - 385) * 256 + t;
    if (i < 256 * 128) split1(W1[i], W1hi[i], W1lo[i]);
    int j = i - 256 * 128;
    if (j >= 0 && j < 256 * 256) split1(W2[j], W2hi[j], W2lo[j]);
  } else {
    int i = (blk - 769) * 256 + t;
    if (i < N_NODES) out64[i] = 0ull;   // zero output (atomic W3 accumulation)
  }
}

// ---------------- fully fused: mask build + 2-layer GAT + 3-layer MLP ----------------
// R14: counters showed latency-bound (MfmaUtil 16%, VALUBusy 17%, Occ 20% at
// 2 waves/SIMD). Now 1024 threads = 16 waves = 4 waves/SIMD: the serial head
// loop is split across wave halves (waves 0-7: heads{0,1}, 8-15: heads{2,3});
// upper waves store partial hacc to LDS pH, lower waves combine+activate.
// Total MFMA work unchanged; per-wave serial path halves. A-dedup is now
// exactly 1 softmax pair per wave. MLP: 16 cols/wave. F planes switch from
// PF=136 pad to XOR swizzle (col ^ ((row&15)<<3), unpadded 128 pitch) to fit
// pH in 160KB LDS; psx/psy/pdx/pdy/m64 reg arrays dropped (read LDS in the
// once-per-layer A-build) to stay under the 128-VGPR cap 1024-thr blocks need.

// LDS layout (ushort offsets), total 74752 ushorts = 149504 B:
//  sFa 0 | sFb 8192 | sFc 16384   (64x128 each, swizzled)
//  pxs 24576 (f32[64]) | pys 24704 (f32[64]) | smask 24832 (u64[64])
//  aA 25088 (32768 ushorts = 64KB, 16 A-frag pairs)   [MLP: pA=aA, pB=aA+16384]
//  pH 57856 (f32[64*132] cross-half partial-hacc exchange, pitch 132)
#define SFB_OFF 8192
#define SFC_OFF 16384
#define PXS_OFF 24576
#define PYS_OFF 24704
#define SMASK_OFF 24832
#define AFRAG_OFF 25088
#define PH_OFF 57856
#define LDS_USHORTS 74752

template <int KD>
__device__ __forceinline__ void gat_layer(
    int wave, int lane, int lm, int lq,
    const ushort* sFa, const ushort* sFb, const ushort* sFc,
    ushort* aA,
    const float* pxs, const float* pys,
    const unsigned long long* smask,
    const float* __restrict__ G,
    const ushort* __restrict__ Ma, const ushort* __restrict__ Mb,
    const ushort* __restrict__ Mc,
    f32x4 hacc[4])
{
  // ---- A-build: wave w owns pair (h = w>>2, mtd = w&3); one softmax per wave.
  {
    int wm = wave & 3;
    int h = wave >> 2;
    float pdxm = pxs[wm * 16 + lm];
    float pdym = pys[wm * 16 + lm];
    unsigned long long mm = smask[wm * 16 + lm];
    unsigned mb0 = (unsigned)((mm >> (8 * lq)) & 0xFF);
    unsigned mb1 = (unsigned)((mm >> (32 + 8 * lq)) & 0xFF);
    float g0 = G[h * 4], g1 = G[h * 4 + 1], g2 = G[h * 4 + 2], g3 = G[h * 4 + 3];
    float a0 = (g0 * pdxm + g2 * pdym) * SCALE_F;
    float a1 = (g1 * pdxm + g3 * pdym) * SCALE_F;
    float sshift = a0 * pdxm + a1 * pdym;
    float e[16];
    float sum = 0.f;
#pragma unroll
    for (int j = 0; j < 8; j++) {
      e[j]     = ((mb0 >> j) & 1) ? __expf(a0 * pxs[8 * lq + j] + a1 * pys[8 * lq + j] - sshift) : 0.f;
      e[8 + j] = ((mb1 >> j) & 1) ? __expf(a0 * pxs[32 + 8 * lq + j] + a1 * pys[32 + 8 * lq + j] - sshift) : 0.f;
      sum += e[j] + e[8 + j];
    }
    sum += __shfl_xor(sum, 16);
    sum += __shfl_xor(sum, 32);
    float inv = 1.f / sum;
    bf16x8 Aa0, Aa1, Ab0, Ab1;
#pragma unroll
    for (int j = 0; j < 8; j++) {
      ushort ua, ub;
      split1(e[j] * inv, ua, ub);     Aa0[j] = (short)ua; Ab0[j] = (short)ub;
      split1(e[8 + j] * inv, ua, ub); Aa1[j] = (short)ua; Ab1[j] = (short)ub;
    }
    int sbase = wave * 2048 + lane * 8;   // pair id h*4+wm == wave
    *(bf16x8*)&aA[sbase]        = Aa0;
    *(bf16x8*)&aA[sbase + 512]  = Aa1;
    *(bf16x8*)&aA[sbase + 1024] = Ab0;
    *(bf16x8*)&aA[sbase + 1536] = Ab1;
  }
  __syncthreads();   // BA: all 16 pairs' A-frags visible

  const int K4 = 4 * KD;
  const int o = 16 * (wave & 7) + lm;
  const int hb = wave >> 3;
#pragma unroll
  for (int i = 0; i < 4; i++) hacc[i] = (f32x4){0.f, 0.f, 0.f, 0.f};

#pragma unroll 1
  for (int hi = 0; hi < 2; hi++) {
    int h = 2 * hb + hi;     // waves 0-7: heads {0,1}; waves 8-15: heads {2,3}
    f32x4 y[4];
#pragma unroll
    for (int i = 0; i < 4; i++) y[i] = (f32x4){0.f, 0.f, 0.f, 0.f};
#pragma unroll 1
    for (int kf = 0; kf < KD / 32; kf++) {
      size_t boff = (size_t)o * K4 + h * KD + kf * 32 + lq * 8;
      bf16x8 ma = *(const bf16x8*)&Ma[boff];
      bf16x8 mb = *(const bf16x8*)&Mb[boff];
      bf16x8 mc = *(const bf16x8*)&Mc[boff];
      int ko = kf * 32 + lq * 8;
      int sw = lm << 3;
#pragma unroll
      for (int mp = 0; mp < 2; mp++) {
        int f0 = (mp * 32 + lm) * 128 + (ko ^ sw);
        int f1 = f0 + 16 * 128;
        bf16x8 fa0 = *(const bf16x8*)&sFa[f0], fa1 = *(const bf16x8*)&sFa[f1];
        bf16x8 fb0 = *(const bf16x8*)&sFb[f0], fb1 = *(const bf16x8*)&sFb[f1];
        bf16x8 fc0 = *(const bf16x8*)&sFc[f0], fc1 = *(const bf16x8*)&sFc[f1];
        f32x4 y0 = y[mp * 2], y1 = y[mp * 2 + 1];
        MFMA(y0, fa0, ma); MFMA(y1, fa1, ma);
        MFMA(y0, fa0, mb); MFMA(y1, fa1, mb);
        MFMA(y0, fb0, ma); MFMA(y1, fb1, ma);
        MFMA(y0, fa0, mc); MFMA(y1, fa1, mc);
        MFMA(y0, fc0, ma); MFMA(y1, fc1, ma);
        MFMA(y0, fb0, mb); MFMA(y1, fb1, mb);
        y[mp * 2] = y0; y[mp * 2 + 1] = y1;
      }
    }
    // redistribute y (C-layout) -> B-frags via shuffles, split2
    bf16x8 Ya[2], Yb[2];
#pragma unroll
    for (int kb = 0; kb < 2; kb++) {
#pragma unroll
      for (int j = 0; j < 8; j++) {
        int sl = ((2 * lq + (j >> 2)) & 3) * 16 + lm;
        float v0 = __shfl(y[2 * kb][j & 3], sl);
        float v1 = __shfl(y[2 * kb + 1][j & 3], sl);
        float v = (lq & 2) ? v1 : v0;
        ushort ua, ub;
        split1(v, ua, ub);
        Ya[kb][j] = (short)ua; Yb[kb][j] = (short)ub;
      }
    }
    // A@Y per dst tile, A-frags from LDS (lane-linear b128, conflict-free)
#pragma unroll
    for (int mtd = 0; mtd < 4; mtd++) {
      int abase = (h * 4 + mtd) * 2048 + lane * 8;
      bf16x8 Aa0 = *(const bf16x8*)&aA[abase];
      bf16x8 Aa1 = *(const bf16x8*)&aA[abase + 512];
      bf16x8 Ab0 = *(const bf16x8*)&aA[abase + 1024];
      bf16x8 Ab1 = *(const bf16x8*)&aA[abase + 1536];
      MFMA(hacc[mtd], Aa0, Ya[0]);
      MFMA(hacc[mtd], Aa0, Yb[0]);
      MFMA(hacc[mtd], Ab0, Ya[0]);
      MFMA(hacc[mtd], Ab0, Yb[0]);
      MFMA(hacc[mtd], Aa1, Ya[1]);
      MFMA(hacc[mtd], Aa1, Yb[1]);
      MFMA(hacc[mtd], Ab1, Ya[1]);
      MFMA(hacc[mtd], Ab1, Yb[1]);
    }
  }
}

__global__ __attribute__((amdgpu_flat_work_group_size(1024, 1024), amdgpu_waves_per_eu(4)))
void fused_gat_kernel(
    const float* __restrict__ x, const float* __restrict__ pos,
    const int* __restrict__ srcp, const int* __restrict__ dstp,
    const float* __restrict__ G,
    const ushort* __restrict__ M0a, const ushort* __restrict__ M0b, const ushort* __restrict__ M0c,
    const ushort* __restrict__ M1a, const ushort* __restrict__ M1b, const ushort* __restrict__ M1c,
    const float* __restrict__ bo0, const float* __restrict__ bo1,
    const ushort* __restrict__ W1hi, const ushort* __restrict__ W1lo, const float* __restrict__ b1,
    const ushort* __restrict__ W2hi, const ushort* __restrict__ W2lo, const float* __restrict__ b2,
    const float* __restrict__ W3, const float* __restrict__ b3,
    float* __restrict__ outp)
{
  __shared__ __align__(16) ushort uBig[LDS_USHORTS];
  ushort* sFa = uBig;
  ushort* sFb = uBig + SFB_OFF;
  ushort* sFc = uBig + SFC_OFF;
  float* pxs = (float*)(uBig + PXS_OFF);
  float* pys = (float*)(uBig + PYS_OFF);
  unsigned long long* smask = (unsigned long long*)(uBig + SMASK_OFF);
  ushort* aA = uBig + AFRAG_OFF;
  ushort* pA = uBig + AFRAG_OFF;            // MLP reuse of A region (dead by then)
  ushort* pB = uBig + AFRAG_OFF + 16384;
  float* pH = (float*)(uBig + PH_OFF);

  int b = blockIdx.x, t = threadIdx.x;
  int wave = t >> 6, lane = t & 63, lm = lane & 15, lq = lane >> 4;

  if (t < 64) {
    pxs[t] = pos[(b * 64 + t) * 2];
    pys[t] = pos[(b * 64 + t) * 2 + 1];
    smask[t] = 1ull << t;   // self-loop bit
  }
  // stage X (64x64 fp32) -> triple-split swizzled planes; one float4/thread
  {
    const float4* gx = (const float4*)(x + (size_t)b * 64 * DIN);
    float4 v = gx[t];
    int r = t >> 4, c = (t & 15) * 4;
    int cs = c ^ ((r & 15) << 3);
    ushort4 ua, ub, uc;
    split3(v.x, ua.x, ub.x, uc.x); split3(v.y, ua.y, ub.y, uc.y);
    split3(v.z, ua.z, ub.z, uc.z); split3(v.w, ua.w, ub.w, uc.w);
    *(ushort4*)&sFa[r * 128 + cs] = ua;
    *(ushort4*)&sFb[r * 128 + cs] = ub;
    *(ushort4*)&sFc[r * 128 + cs] = uc;
  }
  __syncthreads();   // B1: smask init + X visible
  // adjacency from this block's own 448 kNN edge rows (reference (B,A,K) C-order)
  if (t < 448) {
    int s = srcp[b * 448 + t];
    int d = dstp[b * 448 + t];
    atomicOr(&smask[d & 63], 1ull << (s & 63));
  }
  __syncthreads();   // B2

  f32x4 hacc[4];
  gat_layer<DIN>(wave, lane, lm, lq, sFa, sFb, sFc, aA, pxs, pys, smask,
                 G, M0a, M0b, M0c, hacc);
  int o = 16 * (wave & 7) + lm;
  if (wave >= 8) {   // store partial hacc (heads 2,3)
#pragma unroll
    for (int mtd = 0; mtd < 4; mtd++)
#pragma unroll
      for (int r = 0; r < 4; r++)
        pH[(mtd * 16 + lq * 4 + r) * 132 + o] = hacc[mtd][r];
  }
  __syncthreads();   // B3: layer-0 F/A reads done + pH visible
  if (wave < 8) {    // combine halves, activate, store h1 -> F planes
    float bv = bo0[o];
#pragma unroll
    for (int mtd = 0; mtd < 4; mtd++)
#pragma unroll
      for (int r = 0; r < 4; r++) {
        int dst = mtd * 16 + lq * 4 + r;
        float v = tanhf(hacc[mtd][r] + pH[dst * 132 + o] + bv);
        ushort ua, ub, uc;
        split3(v, ua, ub, uc);
        int cs = o ^ ((dst & 15) << 3);
        sFa[dst * 128 + cs] = ua;
        sFb[dst * 128 + cs] = ub;
        sFc[dst * 128 + cs] = uc;
      }
  }
  __syncthreads();   // B4
  gat_layer<HID>(wave, lane, lm, lq, sFa, sFb, sFc, aA, pxs, pys, smask,
                 G + 16, M1a, M1b, M1c, hacc);
  if (wave >= 8) {
#pragma unroll
    for (int mtd = 0; mtd < 4; mtd++)
#pragma unroll
      for (int r = 0; r < 4; r++)
        pH[(mtd * 16 + lq * 4 + r) * 132 + o] = hacc[mtd][r];
  }
  __syncthreads();   // B5
  if (wave < 8) {    // combine, tanh, store h2 split2
    float bv = bo1[o];
#pragma unroll
    for (int mtd = 0; mtd < 4; mtd++)
#pragma unroll
      for (int r = 0; r < 4; r++) {
        int dst = mtd * 16 + lq * 4 + r;
        float v = tanhf(hacc[mtd][r] + pH[dst * 132 + o] + bv);
        ushort hh, ll;
        split1(v, hh, ll);
        int cs = o ^ ((dst & 15) << 3);
        sFa[dst * 128 + cs] = hh;
        sFb[dst * 128 + cs] = ll;
      }
  }
  __syncthreads();   // B6
  // ---- W1: out1 = relu(h2 @ W1^T + b1); 16 waves x 16 cols ----
  f32x4 y1[4];
#pragma unroll
  for (int mtd = 0; mtd < 4; mtd++) y1[mtd] = (f32x4){0.f, 0.f, 0.f, 0.f};
#pragma unroll 1
  for (int kf = 0; kf < 4; kf++) {
    int ko = kf * 32 + lq * 8;
    int col = 16 * wave + lm;
    bf16x8 bh = *(const bf16x8*)&W1hi[(size_t)col * 128 + ko];
    bf16x8 bl = *(const bf16x8*)&W1lo[(size_t)col * 128 + ko];
#pragma unroll
    for (int mtd = 0; mtd < 4; mtd++) {
      int row = mtd * 16 + lm;
      int cs = ko ^ (lm << 3);
      bf16x8 ah = *(const bf16x8*)&sFa[row * 128 + cs];
      bf16x8 al = *(const bf16x8*)&sFb[row * 128 + cs];
      MFMA(y1[mtd], ah, bh);
      MFMA(y1[mtd], ah, bl);
      MFMA(y1[mtd], al, bh);
    }
  }
  // store out1 split2, XOR-swizzled: elem (row,k) at row*256 + (k ^ ((row&15)<<3))
  {
    int col = 16 * wave + lm;
    float bv = b1[col];
#pragma unroll
    for (int mtd = 0; mtd < 4; mtd++)
#pragma unroll
      for (int r = 0; r < 4; r++) {
        int row = mtd * 16 + lq * 4 + r;
        float v = fmaxf(y1[mtd][r] + bv, 0.f);
        ushort hh, ll;
        split1(v, hh, ll);
        int cc = col ^ ((row & 15) << 3);
        pA[row * 256 + cc] = hh;
        pB[row * 256 + cc] = ll;
      }
  }
  __syncthreads();   // B8
  // ---- W2 + fused W3 ----
  f32x4 y2[4];
#pragma unroll
  for (int mtd = 0; mtd < 4; mtd++) y2[mtd] = (f32x4){0.f, 0.f, 0.f, 0.f};
#pragma unroll 1
  for (int kf = 0; kf < 8; kf++) {
    int ko = kf * 32 + lq * 8;
    bf16x8 bh = *(const bf16x8*)&W2hi[(size_t)(16 * wave + lm) * 256 + ko];
    bf16x8 bl = *(const bf16x8*)&W2lo[(size_t)(16 * wave + lm) * 256 + ko];
#pragma unroll
    for (int mtd = 0; mtd < 4; mtd++) {
      int row = mtd * 16 + lm;
      int cc = ko ^ (lm << 3);
      bf16x8 ah = *(const bf16x8*)&pA[row * 256 + cc];
      bf16x8 al = *(const bf16x8*)&pB[row * 256 + cc];
      MFMA(y2[mtd], ah, bh);
      MFMA(y2[mtd], ah, bl);
      MFMA(y2[mtd], al, bh);
    }
  }
  // W3 epilogue: per-row dot over this wave's 16 cols, lm-reduce, atomicAdd
  {
    int c0 = 16 * wave + lm;
    float w30 = W3[c0], w31 = W3[256 + c0];
    float b20 = b2[c0];
    float bb0 = (wave == 0) ? b3[0] : 0.f;
    float bb1 = (wave == 0) ? b3[1] : 0.f;
#pragma unroll
    for (int mtd = 0; mtd < 4; mtd++)
#pragma unroll
      for (int r = 0; r < 4; r++) {
        float va = fmaxf(y2[mtd][r] + b20, 0.f);
        float s0 = va * w30;
        float s1 = va * w31;
        s0 += __shfl_xor(s0, 1); s0 += __shfl_xor(s0, 2);
        s0 += __shfl_xor(s0, 4); s0 += __shfl_xor(s0, 8);
        s1 += __shfl_xor(s1, 1); s1 += __shfl_xor(s1, 2);
        s1 += __shfl_xor(s1, 4); s1 += __shfl_xor(s1, 8);
        if (lm == 0) {
          int row = b * 64 + mtd * 16 + lq * 4 + r;
          atomicAdd(&outp[row * 2 + 0], s0 + bb0);
          atomicAdd(&outp[row * 2 + 1], s1 + bb1);
        }
      }
  }
}

// ---------------- launch ----------------

extern "C" void kernel_launch(void* const* d_in, const int* in_sizes, int n_in,
                              void* d_out, int out_size, void* d_ws, size_t ws_size,
                              hipStream_t stream) {
  const float* x     = (const float*)d_in[0];
  const float* pos   = (const float*)d_in[1];
  const int*   ei    = (const int*)d_in[2];
  const float* l0_Wq = (const float*)d_in[3];
  const float* l0_Wk = (const float*)d_in[4];
  const float* l0_Wv = (const float*)d_in[5];
  const float* l0_Wo = (const float*)d_in[6];
  const float* l0_bo = (const float*)d_in[7];
  const float* l1_Wq = (const float*)d_in[8];
  const float* l1_Wk = (const float*)d_in[9];
  const float* l1_Wv = (const float*)d_in[10];
  const float* l1_Wo = (const float*)d_in[11];
  const float* l1_bo = (const float*)d_in[12];
  const float* W1    = (const float*)d_in[13];
  const float* b1    = (const float*)d_in[14];
  const float* W2    = (const float*)d_in[15];
  const float* b2    = (const float*)d_in[16];
  const float* W3    = (const float*)d_in[17];
  const float* b3    = (const float*)d_in[18];
  float* outp = (float*)d_out;

  int E = in_sizes[2] / 2;
  const int* srcp = ei;
  const int* dstp = ei + E;

  char* base = (char*)d_ws;
  size_t off = 0;
  auto alloc = [&](size_t bytes) -> void* {
    void* p = base + off;
    off = (off + bytes + 255) & ~(size_t)255;
    return p;
  };
  float*  G   = (float*)alloc(32 * sizeof(float));
  ushort* M0a = (ushort*)alloc((size_t)128 * 256 * 2);
  ushort* M0b = (ushort*)alloc((size_t)128 * 256 * 2);
  ushort* M0c = (ushort*)alloc((size_t)128 * 256 * 2);
  ushort* M1a = (ushort*)alloc((size_t)128 * 512 * 2);
  ushort* M1b = (ushort*)alloc((size_t)128 * 512 * 2);
  ushort* M1c = (ushort*)alloc((size_t)128 * 512 * 2);
  ushort* W1hi = (ushort*)alloc((size_t)256 * 128 * 2);
  ushort* W1lo = (ushort*)alloc((size_t)256 * 128 * 2);
  ushort* W2hi = (ushort*)alloc((size_t)256 * 256 * 2);
  ushort* W2lo = (ushort*)alloc((size_t)256 * 256 * 2);

  // prep: G, M folds, W splits, zero(out)
  prep_all_kernel<<<833, 256, 0, stream>>>(
      l0_Wq, l0_Wk, l1_Wq, l1_Wk, G,
      l0_Wv, l0_Wo, M0a, M0b, M0c,
      l1_Wv, l1_Wo, M1a, M1b, M1c,
      W1, W1hi, W1lo, W2, W2hi, W2lo,
      (unsigned long long*)outp);

  // fully fused network: 1024 threads (16 waves), head-split halves
  fused_gat_kernel<<<N_NODES / 64, 1024, 0, stream>>>(
      x, pos, srcp, dstp, G, M0a, M0b, M0c, M1a, M1b, M1c, l0_bo, l1_bo,
      W1hi, W1lo, b1, W2hi, W2lo, b2, W3, b3, outp);

  (void)n_in; (void)out_size; (void)ws_size;
}